// Round 21
// baseline (276.374 us; speedup 1.0000x reference)
//
#include <hip/hip_runtime.h>
#include <cstdint>
#include <cstddef>

// ---------------------------------------------------------------------------
// L4maAttention, fp16 pipeline (round 21 = round 20 + mlb relocated to ws):
//   cvt_h ->
//   gemm_qkv (512 threads/block, 8 waves: fp32 Wq/Wk/Wv in-kernel B-cvt,
//             depth-1 dbuf; 384 GEMM + 128 aux blocks (cache conv + Wo cvt)) ->
//   aux2 (RoPE q/k) ->
//   attn_part (2-way KV-split, round-13 clean core; mlb now in ws) ->
//   gemm_o (o-proj with FUSED flash-decoding combine in A-staging) -> fp32.
// ---------------------------------------------------------------------------

typedef _Float16 f16;
typedef f16 f16x8 __attribute__((ext_vector_type(8)));
typedef f16 f16x4 __attribute__((ext_vector_type(4)));
typedef float f32x4 __attribute__((ext_vector_type(4)));

#define HIDN 4096
#define LCTX 3072
#define PASTN 2048
#define QK_SCALE_LOG2 0.12753102734366334f
#define RESC_THR 11.54f

__device__ __forceinline__ f32x4 mfma16(f16x8 a, f16x8 b, f32x4 c) {
    return __builtin_amdgcn_mfma_f32_16x16x32_f16(a, b, c, 0, 0, 0);
}
__device__ __forceinline__ f32x4 mfma16k16(f16x4 a, f16x4 b, f32x4 c) {
    return __builtin_amdgcn_mfma_f32_16x16x16f16(a, b, c, 0, 0, 0);
}

__device__ __forceinline__ void gl_lds16(const void* g, void* l) {
    auto gp = (const __attribute__((address_space(1))) unsigned int*)(uintptr_t)g;
    auto lp = (__attribute__((address_space(3))) unsigned int*)(uintptr_t)l;
    __builtin_amdgcn_global_load_lds(gp, lp, 16, 0, 0);
}

__device__ __forceinline__ uint32_t lds_lo(const void* p) {
    return (uint32_t)(uintptr_t)p;
}

#define TRRD(dst, va, OFF) \
    asm volatile("ds_read_b64_tr_b16 %0, %1 offset:" #OFF : "=v"(dst) : "v"(va))
#define WAITL(N) \
    asm volatile("s_waitcnt lgkmcnt(" #N ")" ::: "memory"); \
    __builtin_amdgcn_sched_barrier(0)

// ---------------------------------------------------------------------------
// cvt_h: hidden fp32 -> fp16 only (1,048,576 f4 = 4096 x 256)
// ---------------------------------------------------------------------------
__global__ void cvt_h(const float* __restrict__ hidden, f16* __restrict__ h16)
{
    int i = blockIdx.x * 256 + threadIdx.x;
    f32x4 v = *(const f32x4*)(hidden + (size_t)i * 4);
    f16x4 h;
#pragma unroll
    for (int j = 0; j < 4; j++) h[j] = (f16)v[j];
    *(f16x4*)(h16 + (size_t)i * 4) = h;
}

// ---------------------------------------------------------------------------
// gemm_qkv: C[1024,6144] = h16 @ W^T, 512 threads (8 waves, 2x4 wave grid,
// 64x32 per wave). A = h16 f16 via gl_lds (dbuf). B = fp32 Wq/Wk/Wv converted
// in-kernel (depth-1 pipeline). Grid 512: blocks 0..383 GEMM (48x8 tiles of
// 128x128); 384..511 aux (cached-KV conv + Wo fp32->f16 slice).
// ---------------------------------------------------------------------------
__global__ __launch_bounds__(512, 4) void gemm_qkv(
    const f16* __restrict__ A,
    const float* __restrict__ Bq, const float* __restrict__ Bk2,
    const float* __restrict__ Bv2,
    f16* __restrict__ Cq, f16* __restrict__ Ck, f16* __restrict__ Cv,
    const float* __restrict__ kvp, const int* __restrict__ layer,
    f16* __restrict__ ckc, const float* __restrict__ Wo, f16* __restrict__ w16o)
{
    constexpr int K = 4096;
    __shared__ f16 As[2 * 128 * 64];
    __shared__ f16 Bs[2 * 128 * 64];

    const int bx = blockIdx.x;
    const int t = threadIdx.x;

    if (bx >= 384) {
        const int lay = layer[0];
        const int cid = bx - 384;                      // 0..127
        int base = cid * 512 + t;                      // 0..65535
        // ---- cached-KV fp32 -> f16 (1,048,576 f4) ----
#pragma unroll
        for (int pass = 0; pass < 16; ++pass) {
            int i4 = base + pass * 65536;              // 0..1048575
            int half = i4 >> 19;
            int e = (i4 & 524287) * 4;
            int hh = e >> 18, rem = e & 262143, l = rem >> 7, d = rem & 127;
            int blk = l >> 4, rr = l & 15;
            size_t src = (((size_t)(lay * 2 + half) * 256 + blk) * 8 + hh) * 2048
                       + (size_t)rr * 128 + d;
            f32x4 x = *(const f32x4*)(kvp + src);
            f16x4 h;
#pragma unroll
            for (int j = 0; j < 4; j++) h[j] = (f16)x[j];
            size_t dst = ((size_t)hh * LCTX + l) * 128 + d;
            *(f16x4*)((half ? Cv : ckc) + dst) = h;
        }
        // ---- Wo fp32 -> f16 slice (32768 f4 per block) ----
        {
            const float* src = Wo + (size_t)cid * 131072;
            f16* dst = w16o + (size_t)cid * 131072;
#pragma unroll 4
            for (int p = 0; p < 64; ++p) {
                int e = (p * 512 + t) * 4;
                f32x4 v = *(const f32x4*)(src + e);
                f16x4 hv;
#pragma unroll
                for (int jx = 0; jx < 4; jx++) hv[jx] = (f16)v[jx];
                *(f16x4*)(dst + e) = hv;
            }
        }
        return;
    }

    const int lane = t & 63, w = t >> 6;          // w 0..7
    const int wm = w >> 2, wn = w & 3;            // 2 x 4 wave grid
    const int l16 = lane & 15, g16 = lane >> 4;
    const int m0 = (bx / 48) * 128, n0 = (bx % 48) * 128;

    const int srow = lane >> 3;
    const int sgr  = (lane & 7) ^ srow;
    const size_t aoff = (size_t)(m0 + w * 16 + srow) * K + sgr * 8;

    const float* Bf;
    int nb = n0;
    if (n0 >= 5120)      { Bf = Bv2; nb = n0 - 5120; }
    else if (n0 >= 4096) { Bf = Bk2; nb = n0 - 4096; }
    else                 { Bf = Bq; }
    const int brw = lane >> 4;                // 0..3
    const int b4  = lane & 15;
    const int bg  = b4 >> 1, bsub = (b4 & 1) << 2;
    const float* bbase = Bf + (size_t)(nb + w * 16 + brw) * K + b4 * 4;

    int bwr[4];
#pragma unroll
    for (int j = 0; j < 4; j++) {
        int r = w * 16 + j * 4 + brw;
        bwr[j] = r * 64 + ((bg ^ (r & 7)) << 3) + bsub;
    }

    f32x4 acc[4][2];
#pragma unroll
    for (int i = 0; i < 4; i++)
#pragma unroll
        for (int j = 0; j < 2; j++) acc[i][j] = (f32x4){0.f, 0.f, 0.f, 0.f};

    f32x4 bv[4];
    // prologue
#pragma unroll
    for (int j = 0; j < 4; j++)
        bv[j] = *(const f32x4*)(bbase + (size_t)(j * 4) * K);
#pragma unroll
    for (int j = 0; j < 2; j++)
        gl_lds16(A + aoff + (size_t)j * 8 * K,
                 (void*)(As + (w * 16 + j * 8) * 64));
#pragma unroll
    for (int j = 0; j < 4; j++) {
        f16x4 hv;
#pragma unroll
        for (int q = 0; q < 4; q++) hv[q] = (f16)bv[j][q];
        *(f16x4*)&Bs[bwr[j]] = hv;
    }
    __syncthreads();

    for (int k0 = 0; k0 < K; k0 += 64) {
        const int cur = (k0 >> 6) & 1;
        const int nxt = cur ^ 1;
        const bool more = (k0 + 64 < K);
        if (more) {
#pragma unroll
            for (int j = 0; j < 2; j++)
                gl_lds16(A + aoff + (size_t)j * 8 * K + k0 + 64,
                         (void*)(As + nxt * 8192 + (w * 16 + j * 8) * 64));
#pragma unroll
            for (int j = 0; j < 4; j++)
                bv[j] = *(const f32x4*)(bbase + (size_t)(j * 4) * K + k0 + 64);
        }
#pragma unroll
        for (int ks = 0; ks < 2; ks++) {
            f16x8 af[4], bfr[2];
#pragma unroll
            for (int mi = 0; mi < 4; mi++) {
                int r = wm * 64 + mi * 16 + l16;
                int g = ks * 4 + g16;
                af[mi] = *(const f16x8*)&As[cur * 8192 + r * 64 + ((g ^ (r & 7)) << 3)];
            }
#pragma unroll
            for (int ni = 0; ni < 2; ni++) {
                int r = wn * 32 + ni * 16 + l16;
                int g = ks * 4 + g16;
                bfr[ni] = *(const f16x8*)&Bs[cur * 8192 + r * 64 + ((g ^ (r & 7)) << 3)];
            }
#pragma unroll
            for (int ni = 0; ni < 2; ni++)
#pragma unroll
                for (int mi = 0; mi < 4; mi++)
                    acc[mi][ni] = mfma16(af[mi], bfr[ni], acc[mi][ni]);
        }
        if (more) {
#pragma unroll
            for (int j = 0; j < 4; j++) {
                f16x4 hv;
#pragma unroll
                for (int q = 0; q < 4; q++) hv[q] = (f16)bv[j][q];
                *(f16x4*)&Bs[nxt * 8192 + bwr[j]] = hv;
            }
        }
        __syncthreads();
    }

#pragma unroll
    for (int mi = 0; mi < 4; mi++)
#pragma unroll
        for (int ni = 0; ni < 2; ni++)
#pragma unroll
            for (int r = 0; r < 4; r++) {
                int row = m0 + wm * 64 + mi * 16 + (g16 << 2) + r;
                int col = n0 + wn * 32 + ni * 16 + l16;
                float val = acc[mi][ni][r];
                if (col < 4096) {
                    Cq[(size_t)row * 4096 + col] = (f16)val;
                } else if (col < 5120) {
                    Ck[(size_t)row * 1024 + (col - 4096)] = (f16)val;
                } else {
                    int c = col - 5120;
                    int hh = c >> 7, d = c & 127;
                    Cv[((size_t)hh * LCTX + PASTN + row) * 128 + d] = (f16)val;
                }
            }
}

// ---------------------------------------------------------------------------
// aux2: RoPE only. rope_q (262,144) + rope_k (65,536) = 327,680 = 1280 x 256.
// ---------------------------------------------------------------------------
__global__ void aux2(f16* __restrict__ q16, const f16* __restrict__ kraw,
                     const float* __restrict__ cosp, const float* __restrict__ sinp,
                     f16* __restrict__ ck)
{
    int i = blockIdx.x * 256 + threadIdx.x;
    if (i < 262144) {
        int gd = i & 7, hh = (i >> 3) & 31, s = i >> 8;
        size_t b1 = (size_t)s * 4096 + hh * 128 + gd * 8;
        f16x8 x1 = *(f16x8*)(q16 + b1);
        f16x8 x2 = *(f16x8*)(q16 + b1 + 64);
        const float* c1 = cosp + s * 128 + gd * 8;
        const float* s1 = sinp + s * 128 + gd * 8;
        f16x8 o1, o2;
#pragma unroll
        for (int j = 0; j < 8; j++) {
            float a = (float)x1[j], b = (float)x2[j];
            o1[j] = (f16)((a * c1[j] - b * s1[j]) * QK_SCALE_LOG2);
            o2[j] = (f16)((b * c1[j + 64] + a * s1[j + 64]) * QK_SCALE_LOG2);
        }
        *(f16x8*)(q16 + b1) = o1;
        *(f16x8*)(q16 + b1 + 64) = o2;
    } else {
        int ii = i - 262144;
        int gd = ii & 7, kvh = (ii >> 3) & 7, s = ii >> 6;
        size_t b1 = (size_t)s * 1024 + kvh * 128 + gd * 8;
        f16x8 x1 = *(const f16x8*)(kraw + b1);
        f16x8 x2 = *(const f16x8*)(kraw + b1 + 64);
        const float* c1 = cosp + s * 128 + gd * 8;
        const float* s1 = sinp + s * 128 + gd * 8;
        f16x8 o1, o2;
#pragma unroll
        for (int j = 0; j < 8; j++) {
            float a = (float)x1[j], b = (float)x2[j];
            o1[j] = (f16)(a * c1[j] - b * s1[j]);
            o2[j] = (f16)(b * c1[j + 64] + a * s1[j + 64]);
        }
        size_t dst = ((size_t)kvh * LCTX + PASTN + s) * 128 + gd * 8;
        *(f16x8*)(ck + dst) = o1;
        *(f16x8*)(ck + dst + 64) = o2;
    }
}

// ---------------------------------------------------------------------------
// Flash attention PARTIAL: 2-way KV-split, KVBLK=64 (round-13 clean core).
// Grid 512: z=b>>8, idx=b&255, h=idx&31, jj=idx>>5, j = z?7-jj:jj, s0=j*128.
// ---------------------------------------------------------------------------
__global__ __launch_bounds__(256, 2) void attn_part(
    const f16* __restrict__ Q, const f16* __restrict__ Kc,
    const f16* __restrict__ Vc, f16* __restrict__ Op, float* __restrict__ mlb)
{
    const int b = blockIdx.x;
    const int z = b >> 8;
    const int idx = b & 255;
    const int h = idx & 31;
    const int jj = idx >> 5;
    const int j = z ? (7 - jj) : jj;
    const int s0 = j * 128;
    const int kvh = h >> 2;
    const int t = threadIdx.x, lane = t & 63, w = t >> 6;
    const int l16 = lane & 15, g16 = lane >> 4;

    __shared__ f16 Ks[2][64 * 128];
    __shared__ f16 Vs[2][64 * 128];

    f16x8 qfA[4], qfB[4];
    {
        size_t baseA = (size_t)(s0 + w * 32 + l16) * 4096 + h * 128;
        size_t baseB = baseA + (size_t)16 * 4096;
#pragma unroll
        for (int kk = 0; kk < 4; kk++) {
            qfA[kk] = *(const f16x8*)(Q + baseA + kk * 32 + g16 * 8);
            qfB[kk] = *(const f16x8*)(Q + baseB + kk * 32 + g16 * 8);
        }
    }

    f32x4 ofA[8], ofB[8];
#pragma unroll
    for (int cf = 0; cf < 8; cf++) {
        ofA[cf] = (f32x4){0.f, 0.f, 0.f, 0.f};
        ofB[cf] = (f32x4){0.f, 0.f, 0.f, 0.f};
    }
    float mrA = -3.0e38f, lrA = 0.f;
    float mrB = -3.0e38f, lrB = 0.f;

    const f16* Kb = Kc + (size_t)kvh * LCTX * 128;
    const f16* Vb = Vc + (size_t)kvh * LCTX * 128;
    const int ntt = (PASTN + s0 + 128) >> 6;    // even

    const int krow = lane >> 4;
    const int kp   = lane & 15;
    const int vrow = ((lane >> 5) << 4) + (((lane >> 3) & 3) << 2) + ((lane >> 1) & 3);
    const int vch  = (lane & 1) << 3;

    const uint32_t vs0 = lds_lo(Vs[0]) + lane * 8;
    const uint32_t vs1 = lds_lo(Vs[1]) + lane * 8;

#define STAGE_KV(l0, buf)                                                     \
    {                                                                         \
        _Pragma("unroll")                                                     \
        for (int jx = 0; jx < 4; jx++) {                                      \
            int r7 = ((jx & 1) << 2) + krow;                                  \
            int sg = kp ^ r7;                                                 \
            gl_lds16(Kb + (size_t)((l0) + w * 16 + jx * 4 + krow) * 128 + sg * 8, \
                     (void*)(Ks[buf] + (w * 16 + jx * 4) * 128));             \
        }                                                                     \
        _Pragma("unroll")                                                     \
        for (int q = 0; q < 4; q++) {                                         \
            gl_lds16(Vb + (size_t)((l0) + (q & 1) * 32 + vrow) * 128          \
                        + (w * 2 + (q >> 1)) * 16 + vch,                      \
                     (void*)(Vs[buf] + (w * 4 + q) * 512));                   \
        }                                                                     \
    }

    STAGE_KV(z * 64, 0);
    __syncthreads();

    int itp = 0;
    for (int it = z; it < ntt; it += 2, ++itp) {
        const int l0 = it << 6;
        const int cur = itp & 1;

        if (it + 2 < ntt) STAGE_KV(l0 + 128, cur ^ 1);

        f32x4 sA[4], sB[4];
#pragma unroll
        for (int ni = 0; ni < 4; ni++) {
            sA[ni] = (f32x4){0.f, 0.f, 0.f, 0.f};
            sB[ni] = (f32x4){0.f, 0.f, 0.f, 0.f};
        }
        __builtin_amdgcn_s_setprio(1);
#pragma unroll
        for (int ni = 0; ni < 4; ni++)
#pragma unroll
            for (int kk = 0; kk < 4; kk++) {
                int r = ni * 16 + l16;
                int g = kk * 4 + g16;
                f16x8 kh = *(const f16x8*)&Ks[cur][r * 128 + ((g ^ (r & 7)) << 3)];
                sA[ni] = mfma16(kh, qfA[kk], sA[ni]);
                sB[ni] = mfma16(kh, qfB[kk], sB[ni]);
            }
        __builtin_amdgcn_s_setprio(0);

#define SOFTMAX(sf, mr, lr, of, QOFF)                                          \
        {                                                                      \
            const int qrow = s0 + w * 32 + (QOFF) + l16;                       \
            if (l0 + 63 > PASTN + s0 + w * 32 + (QOFF)) {                      \
                _Pragma("unroll")                                              \
                for (int ni = 0; ni < 4; ni++)                                 \
                    _Pragma("unroll")                                          \
                    for (int r = 0; r < 4; r++) {                              \
                        int col = l0 + ni * 16 + (g16 << 2) + r;               \
                        if (col > PASTN + qrow) sf[ni][r] = -3.0e38f;          \
                    }                                                          \
            }                                                                  \
            float mx;                                                          \
            {                                                                  \
                f32x4 m4 = sf[0];                                              \
                _Pragma("unroll")                                              \
                for (int ni = 1; ni < 4; ni++) {                               \
                    m4[0] = fmaxf(m4[0], sf[ni][0]);                           \
                    m4[1] = fmaxf(m4[1], sf[ni][1]);                           \
                    m4[2] = fmaxf(m4[2], sf[ni][2]);                           \
                    m4[3] = fmaxf(m4[3], sf[ni][3]);                           \
                }                                                              \
                mx = fmaxf(fmaxf(m4[0], m4[1]), fmaxf(m4[2], m4[3]));          \
            }                                                                  \
            mx = fmaxf(mx, __shfl_xor(mx, 16));                                \
            mx = fmaxf(mx, __shfl_xor(mx, 32));                                \
            if (__any(mx > mr + RESC_THR)) {                                   \
                float mnew = fmaxf(mr, mx);                                    \
                float corr = exp2f(mr - mnew);                                 \
                mr = mnew;                                                     \
                lr *= corr;                                                    \
                float cr[4];                                                   \
                _Pragma("unroll")                                              \
                for (int r = 0; r < 4; r++) cr[r] = __shfl(corr, (g16 << 2) + r); \
                _Pragma("unroll")                                              \
                for (int cf = 0; cf < 8; cf++)                                 \
                    _Pragma("unroll")                                          \
                    for (int r = 0; r < 4; r++) of[cf][r] *= cr[r];            \
            }                                                                  \
            _Pragma("unroll")                                                  \
            for (int ni = 0; ni < 4; ni++)                                     \
                _Pragma("unroll")                                              \
                for (int r = 0; r < 4; r++) {                                  \
                    float p = exp2f(sf[ni][r] - mr);                           \
                    sf[ni][r] = p;                                             \
                    lr += p;                                                   \
                }                                                              \
        }

        SOFTMAX(sA, mrA, lrA, ofA, 0)
        SOFTMAX(sB, mrB, lrB, ofB, 16)

        f16x4 paA[4], paB[4];
#pragma unroll
        for (int ni = 0; ni < 4; ni++) {
            paA[ni][0] = (f16)sA[ni][0]; paA[ni][1] = (f16)sA[ni][1];
            paA[ni][2] = (f16)sA[ni][2]; paA[ni][3] = (f16)sA[ni][3];
            paB[ni][0] = (f16)sB[ni][0]; paB[ni][1] = (f16)sB[ni][1];
            paB[ni][2] = (f16)sB[ni][2]; paB[ni][3] = (f16)sB[ni][3];
        }

        {
            const uint32_t va = cur ? vs1 : vs0;
            f16x4 ra0, ra1, ra2, ra3, rb0, rb1, rb2, rb3;
            f16x4 rc0, rc1, rc2, rc3, rd0, rd1, rd2, rd3;
            __builtin_amdgcn_s_setprio(1);
            TRRD(ra0,va,0);     TRRD(ra1,va,512);   TRRD(ra2,va,1024);  TRRD(ra3,va,1536);
            TRRD(rb0,va,2048);  TRRD(rb1,va,2560);  TRRD(rb2,va,3072);  TRRD(rb3,va,3584);
            TRRD(rc0,va,4096);  TRRD(rc1,va,4608);  TRRD(rc2,va,5120);  TRRD(rc3,va,5632);
#define X2(cf, ni, reg) \
            ofA[cf] = mfma16k16(paA[ni], reg, ofA[cf]); \
            ofB[cf] = mfma16k16(paB[ni], reg, ofB[cf]);
            WAITL(8);
            X2(0,0,ra0) X2(0,1,ra1) X2(0,2,ra2) X2(0,3,ra3)
            TRRD(rd0,va,6144);  TRRD(rd1,va,6656);  TRRD(rd2,va,7168);  TRRD(rd3,va,7680);
            WAITL(8);
            X2(1,0,rb0) X2(1,1,rb1) X2(1,2,rb2) X2(1,3,rb3)
            TRRD(ra0,va,8192);  TRRD(ra1,va,8704);  TRRD(ra2,va,9216);  TRRD(ra3,va,9728);
            WAITL(8);
            X2(2,0,rc0) X2(2,1,rc1) X2(2,2,rc2) X2(2,3,rc3)
            TRRD(rb0,va,10240); TRRD(rb1,va,10752); TRRD(rb2,va,11264); TRRD(rb3,va,11776);
            WAITL(8);
            X2(3,0,rd0) X2(3,1,rd1) X2(3,2,rd2) X2(3,3,rd3)
            TRRD(rc0,va,12288); TRRD(rc1,va,12800); TRRD(rc2,va,13312); TRRD(rc3,va,13824);
            WAITL(8);
            X2(4,0,ra0) X2(4,1,ra1) X2(4,2,ra2) X2(4,3,ra3)
            TRRD(rd0,va,14336); TRRD(rd1,va,14848); TRRD(rd2,va,15360); TRRD(rd3,va,15872);
            WAITL(8);
            X2(5,0,rb0) X2(5,1,rb1) X2(5,2,rb2) X2(5,3,rb3)
            WAITL(4);
            X2(6,0,rc0) X2(6,1,rc1) X2(6,2,rc2) X2(6,3,rc3)
            WAITL(0);
            X2(7,0,rd0) X2(7,1,rd1) X2(7,2,rd2) X2(7,3,rd3)
#undef X2
            __builtin_amdgcn_s_setprio(0);
        }
        __syncthreads();
    }

#define WRITE_P(of, mr, lr, QOFF)                                             \
    {                                                                         \
        float l2 = lr + __shfl_xor(lr, 16);                                   \
        l2 += __shfl_xor(l2, 32);                                             \
        if (lane < 16) {                                                      \
            int srow = s0 + w * 32 + (QOFF) + lane;                           \
            *(float2*)(mlb + (((size_t)z * 1024 + srow) * 32 + h) * 2) =      \
                make_float2(mr, l2);                                          \
        }                                                                     \
        float lrr[4];                                                         \
        _Pragma("unroll")                                                     \
        for (int r = 0; r < 4; r++) lrr[r] = __shfl(l2, (g16 << 2) + r);      \
        _Pragma("unroll")                                                     \
        for (int cf = 0; cf < 8; cf++)                                        \
            _Pragma("unroll")                                                 \
            for (int r = 0; r < 4; r++) {                                     \
                int srow = s0 + w * 32 + (QOFF) + (g16 << 2) + r;             \
                int d = cf * 16 + l16;                                        \
                Op[(size_t)z * 4194304 + (size_t)srow * 4096                  \
                   + (size_t)h * 128 + d] = (f16)(of[cf][r] / lrr[r]);        \
            }                                                                 \
    }
    WRITE_P(ofA, mrA, lrA, 0)
    WRITE_P(ofB, mrB, lrB, 16)
#undef WRITE_P
#undef SOFTMAX
#undef STAGE_KV
}

// ---------------------------------------------------------------------------
// gemm_o: d_out[1024,4096] fp32 = combine(opart0, opart1) @ Wo16^T.
// 256 threads, BM=64, grid 512 (32x16 tiles). A-staging FUSES the
// flash-decoding combine (reads mlb, which now lives in ws — no aliasing
// with the fp32 output in d_out).
// ---------------------------------------------------------------------------
__global__ __launch_bounds__(256, 3) void gemm_o(
    const f16* __restrict__ Op, const float* __restrict__ mlb,
    const f16* __restrict__ Bh, float* __restrict__ Cf)
{
    constexpr int K = 4096;
    __shared__ f16 As[64 * 64];
    __shared__ f16 Bs[128 * 64];

    const int bx = blockIdx.x;
    const int t = threadIdx.x, lane = t & 63, w = t >> 6;
    const int wm = w >> 1, wn = w & 1;
    const int l16 = lane & 15, g16 = lane >> 4;
    const int m0 = (bx / 32) * 64, n0 = (bx % 32) * 128;

    const int srow = lane >> 3;
    const int sgr  = (lane & 7) ^ srow;

    const size_t boff16 = (size_t)(n0 + w * 32 + srow) * K + sgr * 8;

    f32x4 acc[2][4];
#pragma unroll
    for (int i = 0; i < 2; i++)
#pragma unroll
        for (int j = 0; j < 4; j++) acc[i][j] = (f32x4){0.f, 0.f, 0.f, 0.f};

    for (int k0 = 0; k0 < K; k0 += 64) {
        // ---- A staging with fused combine ----
        {
            const int hh = k0 >> 7;
#pragma unroll
            for (int j = 0; j < 2; j++) {
                int row = m0 + w * 16 + j * 8 + srow;
                int col = k0 + sgr * 8;
                float2 ml0 = *(const float2*)(mlb + (((size_t)row) * 32 + hh) * 2);
                float2 ml1 = *(const float2*)(mlb + (((size_t)1024 + row) * 32 + hh) * 2);
                float mstar = fmaxf(ml0.x, ml1.x);
                float w0 = exp2f(ml0.x - mstar) * ml0.y;
                float w1 = exp2f(ml1.x - mstar) * ml1.y;
                float inv = 1.0f / (w0 + w1);
                w0 *= inv; w1 *= inv;
                f16x8 a0 = *(const f16x8*)(Op + (size_t)row * 4096 + col);
                f16x8 a1 = *(const f16x8*)(Op + 4194304 + (size_t)row * 4096 + col);
                f16x8 av;
#pragma unroll
                for (int q = 0; q < 8; q++)
                    av[q] = (f16)((float)a0[q] * w0 + (float)a1[q] * w1);
                *(f16x8*)&As[(w * 16 + j * 8) * 64 + lane * 8] = av;
            }
        }
        // ---- B staging (f16 Wo via gl_lds) ----
#pragma unroll
        for (int j = 0; j < 4; j++)
            gl_lds16(Bh + boff16 + (size_t)j * 8 * K + k0,
                     (void*)(Bs + (w * 32 + j * 8) * 64));
        __syncthreads();

#pragma unroll
        for (int ks = 0; ks < 2; ks++) {
            f16x8 af[2], bfr[4];
#pragma unroll
            for (int mi = 0; mi < 2; mi++) {
                int r = wm * 32 + mi * 16 + l16;
                int g = ks * 4 + g16;
                af[mi] = *(const f16x8*)&As[r * 64 + ((g ^ (r & 7)) << 3)];
            }
#pragma unroll
            for (int ni = 0; ni < 4; ni++) {
                int r = wn * 64 + ni * 16 + l16;
                int g = ks * 4 + g16;
                bfr[ni] = *(const f16x8*)&Bs[r * 64 + ((g ^ (r & 7)) << 3)];
            }
#pragma unroll
            for (int ni = 0; ni < 4; ni++)
#pragma unroll
                for (int mi = 0; mi < 2; mi++)
                    acc[mi][ni] = mfma16(af[mi], bfr[ni], acc[mi][ni]);
        }
        __syncthreads();
    }

#pragma unroll
    for (int mi = 0; mi < 2; mi++)
#pragma unroll
        for (int ni = 0; ni < 4; ni++)
#pragma unroll
            for (int r = 0; r < 4; r++) {
                int row = m0 + wm * 32 + mi * 16 + (g16 << 2) + r;
                int col = n0 + wn * 64 + ni * 16 + l16;
                Cf[(size_t)row * 4096 + col] = acc[mi][ni][r];
            }
}

// ---------------------------------------------------------------------------
// launcher
// ---------------------------------------------------------------------------
extern "C" void kernel_launch(void* const* d_in, const int* in_sizes, int n_in,
                              void* d_out, int out_size, void* d_ws, size_t ws_size,
                              hipStream_t stream)
{
    const float* hidden = (const float*)d_in[0];
    const float* kvp    = (const float*)d_in[1];
    const float* cosp   = (const float*)d_in[7];
    const float* sinp   = (const float*)d_in[8];
    const float* Wq     = (const float*)d_in[9];
    const float* Wk     = (const float*)d_in[10];
    const float* Wv     = (const float*)d_in[11];
    const float* Wo     = (const float*)d_in[12];
    const int*   layer  = (const int*)d_in[13];

    char* ws = (char*)d_ws;
    f16*   w16  = (f16*)ws;                   // [0,32): Wo f16 (gemm_qkv aux)
    f16*   opart= (f16*)(ws + 33554432);      // 16 MB: attn O partials (z=0,1)
    f16*   h16  = (f16*)(ws + 50331648);      //  8 MB: hidden fp16
    f16*   ck   = (f16*)(ws + 58720256);      //  6 MB: K cache fp16
    f16*   cv   = (f16*)(ws + 65011712);      //  6 MB: V cache fp16
    float* mlb  = (float*)(ws + 71303168);    // 512 KB: (m,l) partials — in ws,
                                              // NO aliasing with d_out output

    f16* q16  = (f16*)d_out;                      // 8 MB scratch in d_out
    f16* kraw = (f16*)((char*)d_out + 8388608);   // 2 MB; dead after aux2

    // 1) hidden fp32 -> fp16
    cvt_h<<<4096, 256, 0, stream>>>(hidden, h16);

    // 2) QKV projection (512 threads, 8 waves) + aux (cache conv + Wo cvt)
    gemm_qkv<<<dim3(512), 512, 0, stream>>>(
        h16, Wq, Wk, Wv, q16, kraw, cv, kvp, layer, ck, Wo, w16);

    // 3) RoPE q/k
    aux2<<<1280, 256, 0, stream>>>(q16, kraw, cosp, sinp, ck);

    // 4) flash attention partial (clean critical path)
    attn_part<<<dim3(512), 256, 0, stream>>>(q16, ck, cv, opart, mlb);

    // 5) output projection with fused combine -> d_out fp32
    gemm_o<<<dim3(512), 256, 0, stream>>>(opart, mlb, w16, (float*)d_out);
}

// Round 22
// 244.547 us; speedup vs baseline: 1.1301x; 1.1301x over previous
//
#include <hip/hip_runtime.h>
#include <cstdint>
#include <cstddef>

// ---------------------------------------------------------------------------
// L4maAttention, fp16 pipeline (round 22 = round 19 exact, measured best):
//   cvt_h (hidden only) ->
//   gemm<0> (fp32 Wq/Wk/Wv, in-kernel B-cvt, depth-1 dbuf pipeline;
//            384 GEMM blocks + 128 aux blocks (cached-KV conv + Wo cvt)) ->
//   aux2 (RoPE q/k) ->
//   attn_part (2-way KV-split, clean critical path) ->
//   combine -> gemm<1> O-proj (split-M 64, f16 Wo) -> d_out fp32.
// ---------------------------------------------------------------------------

typedef _Float16 f16;
typedef f16 f16x8 __attribute__((ext_vector_type(8)));
typedef f16 f16x4 __attribute__((ext_vector_type(4)));
typedef float f32x4 __attribute__((ext_vector_type(4)));

#define HIDN 4096
#define LCTX 3072
#define PASTN 2048
#define QK_SCALE_LOG2 0.12753102734366334f
#define RESC_THR 11.54f

__device__ __forceinline__ f32x4 mfma16(f16x8 a, f16x8 b, f32x4 c) {
    return __builtin_amdgcn_mfma_f32_16x16x32_f16(a, b, c, 0, 0, 0);
}
__device__ __forceinline__ f32x4 mfma16k16(f16x4 a, f16x4 b, f32x4 c) {
    return __builtin_amdgcn_mfma_f32_16x16x16f16(a, b, c, 0, 0, 0);
}

__device__ __forceinline__ void gl_lds16(const void* g, void* l) {
    auto gp = (const __attribute__((address_space(1))) unsigned int*)(uintptr_t)g;
    auto lp = (__attribute__((address_space(3))) unsigned int*)(uintptr_t)l;
    __builtin_amdgcn_global_load_lds(gp, lp, 16, 0, 0);
}

__device__ __forceinline__ uint32_t lds_lo(const void* p) {
    return (uint32_t)(uintptr_t)p;
}

#define TRRD(dst, va, OFF) \
    asm volatile("ds_read_b64_tr_b16 %0, %1 offset:" #OFF : "=v"(dst) : "v"(va))
#define WAITL(N) \
    asm volatile("s_waitcnt lgkmcnt(" #N ")" ::: "memory"); \
    __builtin_amdgcn_sched_barrier(0)

// ---------------------------------------------------------------------------
// cvt_h: hidden fp32 -> fp16 only (1,048,576 f4 = 4096 x 256)
// ---------------------------------------------------------------------------
__global__ void cvt_h(const float* __restrict__ hidden, f16* __restrict__ h16)
{
    int i = blockIdx.x * 256 + threadIdx.x;
    f32x4 v = *(const f32x4*)(hidden + (size_t)i * 4);
    f16x4 h;
#pragma unroll
    for (int j = 0; j < 4; j++) h[j] = (f16)v[j];
    *(f16x4*)(h16 + (size_t)i * 4) = h;
}

// ---------------------------------------------------------------------------
// GEMM: C[M,N] = A[M,K] @ B[N,K]^T.
// EPI 0 (BM=128): A = h16 (f16, gl_lds, dbuf); B = fp32 Wq/Wk/Wv converted
//   in-kernel (depth-1 pipeline). Grid 512:
//   blocks 0..383 = GEMM (48x8 tiles);
//   blocks 384..511 = aux: cached-KV fp32->f16 AND Wo fp32->f16 slice.
// EPI 1 (BM=64): A,B f16 via gl_lds, single-buffer; fp32 C. Grid 512.
// ---------------------------------------------------------------------------
template <int EPI, int BM>
__global__ __launch_bounds__(256, EPI == 0 ? 2 : 3) void gemm_f16(
    const f16* __restrict__ A, const f16* __restrict__ Bh,
    const float* __restrict__ Bq, const float* __restrict__ Bk2,
    const float* __restrict__ Bv2,
    float* __restrict__ Cf, f16* __restrict__ Cq, f16* __restrict__ Ck,
    f16* __restrict__ Cv, int M, int N, int K,
    const float* __restrict__ kvp, const int* __restrict__ layer,
    f16* __restrict__ ckc, const float* __restrict__ Wo, f16* __restrict__ w16o)
{
    __shared__ f16 As[(EPI == 0 ? 2 : 1) * BM * 64];
    __shared__ f16 Bs[(EPI == 0 ? 2 : 1) * 128 * 64];

    const int bx = blockIdx.x;

    if (EPI == 0 && bx >= 384) {
        const int lay = layer[0];
        const int cid = bx - 384;                      // 0..127
        int base = cid * 256 + threadIdx.x;            // 0..32767
        // ---- cached-KV fp32 -> f16 (1,048,576 f4 over 128 blocks) ----
#pragma unroll
        for (int pass = 0; pass < 32; ++pass) {
            int i4 = base + pass * 32768;              // 0..1048575
            int half = i4 >> 19;
            int e = (i4 & 524287) * 4;
            int hh = e >> 18, rem = e & 262143, l = rem >> 7, d = rem & 127;
            int blk = l >> 4, rr = l & 15;
            size_t src = (((size_t)(lay * 2 + half) * 256 + blk) * 8 + hh) * 2048
                       + (size_t)rr * 128 + d;
            f32x4 x = *(const f32x4*)(kvp + src);
            f16x4 h;
#pragma unroll
            for (int j = 0; j < 4; j++) h[j] = (f16)x[j];
            size_t dst = ((size_t)hh * LCTX + l) * 128 + d;
            *(f16x4*)((half ? Cv : ckc) + dst) = h;
        }
        // ---- Wo fp32 -> f16 slice (4,194,304 f4 over 128 blocks) ----
        {
            const float* src = Wo + (size_t)cid * 131072;   // 32768 f4
            f16* dst = w16o + (size_t)cid * 131072;
#pragma unroll 4
            for (int p = 0; p < 128; ++p) {
                int e = (p * 256 + threadIdx.x) * 4;
                f32x4 v = *(const f32x4*)(src + e);
                f16x4 hv;
#pragma unroll
                for (int jx = 0; jx < 4; jx++) hv[jx] = (f16)v[jx];
                *(f16x4*)(dst + e) = hv;
            }
        }
        return;
    }

    constexpr int RPW = BM / 4;
    constexpr int MI  = BM / 32;

    const int t = threadIdx.x, lane = t & 63, w = t >> 6;
    const int wm = w >> 1, wn = w & 1;
    const int l16 = lane & 15, g16 = lane >> 4;
    const int nx = (EPI == 0) ? 48 : 32;
    const int m0 = (bx / nx) * BM, n0 = (bx % nx) * 128;

    const int srow = lane >> 3;
    const int sgr  = (lane & 7) ^ srow;

    const size_t aoff = (size_t)(m0 + w * RPW + srow) * K + sgr * 8;

    f32x4 acc[MI][4];
#pragma unroll
    for (int i = 0; i < MI; i++)
#pragma unroll
        for (int j = 0; j < 4; j++) acc[i][j] = (f32x4){0.f, 0.f, 0.f, 0.f};

    if (EPI == 0) {
        // ---- depth-1 pipelined path: fp32 B, explicit double buffer ----
        const float* Bf;
        int nb = n0;
        if (n0 >= 5120)      { Bf = Bv2; nb = n0 - 5120; }
        else if (n0 >= 4096) { Bf = Bk2; nb = n0 - 4096; }
        else                 { Bf = Bq; }
        const int brw = lane >> 4;                // 0..3 row within 4-row group
        const int b4  = lane & 15;                // f32x4 column slot
        const int bg  = b4 >> 1, bsub = (b4 & 1) << 2;
        const float* bbase = Bf + (size_t)(nb + w * 32 + brw) * K + b4 * 4;

        int bwr[8];
#pragma unroll
        for (int j = 0; j < 8; j++) {
            int r = w * 32 + j * 4 + brw;
            bwr[j] = r * 64 + ((bg ^ (r & 7)) << 3) + bsub;
        }

        f32x4 bv[8];
        // prologue: tile 0
#pragma unroll
        for (int j = 0; j < 8; j++)
            bv[j] = *(const f32x4*)(bbase + (size_t)(j * 4) * K);
#pragma unroll
        for (int j = 0; j < 4; j++)
            gl_lds16(A + aoff + (size_t)j * 8 * K,
                     (void*)(As + (w * 32 + j * 8) * 64));
#pragma unroll
        for (int j = 0; j < 8; j++) {
            f16x4 hv;
#pragma unroll
            for (int q = 0; q < 4; q++) hv[q] = (f16)bv[j][q];
            *(f16x4*)&Bs[bwr[j]] = hv;
        }
        __syncthreads();

        for (int k0 = 0; k0 < K; k0 += 64) {
            const int cur = (k0 >> 6) & 1;
            const int nxt = cur ^ 1;
            const bool more = (k0 + 64 < K);
            if (more) {
#pragma unroll
                for (int j = 0; j < 4; j++)
                    gl_lds16(A + aoff + (size_t)j * 8 * K + k0 + 64,
                             (void*)(As + nxt * (BM * 64) + (w * 32 + j * 8) * 64));
#pragma unroll
                for (int j = 0; j < 8; j++)
                    bv[j] = *(const f32x4*)(bbase + (size_t)(j * 4) * K + k0 + 64);
            }
#pragma unroll
            for (int ks = 0; ks < 2; ks++) {
                f16x8 af[MI], bfr[4];
#pragma unroll
                for (int mi = 0; mi < MI; mi++) {
                    int r = wm * (BM / 2) + mi * 16 + l16;
                    int g = ks * 4 + g16;
                    af[mi] = *(const f16x8*)&As[cur * (BM * 64) + r * 64 + ((g ^ (r & 7)) << 3)];
                }
#pragma unroll
                for (int ni = 0; ni < 4; ni++) {
                    int r = wn * 64 + ni * 16 + l16;
                    int g = ks * 4 + g16;
                    bfr[ni] = *(const f16x8*)&Bs[cur * 8192 + r * 64 + ((g ^ (r & 7)) << 3)];
                }
#pragma unroll
                for (int ni = 0; ni < 4; ni++)
#pragma unroll
                    for (int mi = 0; mi < MI; mi++)
                        acc[mi][ni] = mfma16(af[mi], bfr[ni], acc[mi][ni]);
            }
            if (more) {
#pragma unroll
                for (int j = 0; j < 8; j++) {
                    f16x4 hv;
#pragma unroll
                    for (int q = 0; q < 4; q++) hv[q] = (f16)bv[j][q];
                    *(f16x4*)&Bs[nxt * 8192 + bwr[j]] = hv;
                }
            }
            __syncthreads();
        }
    } else {
        // ---- single-buffer f16 path (o-proj) ----
        const size_t boff16 = (size_t)(n0 + w * 32 + srow) * K + sgr * 8;
        for (int k0 = 0; k0 < K; k0 += 64) {
#pragma unroll
            for (int j = 0; j < RPW / 8; j++)
                gl_lds16(A + aoff + (size_t)j * 8 * K + k0,
                         (void*)(As + (w * RPW + j * 8) * 64));
#pragma unroll
            for (int j = 0; j < 4; j++)
                gl_lds16(Bh + boff16 + (size_t)j * 8 * K + k0,
                         (void*)(Bs + (w * 32 + j * 8) * 64));
            __syncthreads();

#pragma unroll
            for (int ks = 0; ks < 2; ks++) {
                f16x8 af[MI], bfr[4];
#pragma unroll
                for (int mi = 0; mi < MI; mi++) {
                    int r = wm * (BM / 2) + mi * 16 + l16;
                    int g = ks * 4 + g16;
                    af[mi] = *(const f16x8*)&As[r * 64 + ((g ^ (r & 7)) << 3)];
                }
#pragma unroll
                for (int ni = 0; ni < 4; ni++) {
                    int r = wn * 64 + ni * 16 + l16;
                    int g = ks * 4 + g16;
                    bfr[ni] = *(const f16x8*)&Bs[r * 64 + ((g ^ (r & 7)) << 3)];
                }
#pragma unroll
                for (int ni = 0; ni < 4; ni++)
#pragma unroll
                    for (int mi = 0; mi < MI; mi++)
                        acc[mi][ni] = mfma16(af[mi], bfr[ni], acc[mi][ni]);
            }
            __syncthreads();
        }
    }

#pragma unroll
    for (int mi = 0; mi < MI; mi++)
#pragma unroll
        for (int ni = 0; ni < 4; ni++)
#pragma unroll
            for (int r = 0; r < 4; r++) {
                int row = m0 + wm * (BM / 2) + mi * 16 + (g16 << 2) + r;
                int col = n0 + wn * 64 + ni * 16 + l16;
                float val = acc[mi][ni][r];
                if (EPI == 0) {
                    if (col < 4096) {
                        Cq[(size_t)row * 4096 + col] = (f16)val;
                    } else if (col < 5120) {
                        Ck[(size_t)row * 1024 + (col - 4096)] = (f16)val;
                    } else {
                        int c = col - 5120;
                        int hh = c >> 7, d = c & 127;
                        Cv[((size_t)hh * LCTX + PASTN + row) * 128 + d] = (f16)val;
                    }
                } else {
                    Cf[(size_t)row * N + col] = val;
                }
            }
}

// ---------------------------------------------------------------------------
// aux2: RoPE only. rope_q (262,144) + rope_k (65,536) = 327,680 = 1280 x 256.
// ---------------------------------------------------------------------------
__global__ void aux2(f16* __restrict__ q16, const f16* __restrict__ kraw,
                     const float* __restrict__ cosp, const float* __restrict__ sinp,
                     f16* __restrict__ ck)
{
    int i = blockIdx.x * 256 + threadIdx.x;
    if (i < 262144) {
        int gd = i & 7, hh = (i >> 3) & 31, s = i >> 8;
        size_t b1 = (size_t)s * 4096 + hh * 128 + gd * 8;
        f16x8 x1 = *(f16x8*)(q16 + b1);
        f16x8 x2 = *(f16x8*)(q16 + b1 + 64);
        const float* c1 = cosp + s * 128 + gd * 8;
        const float* s1 = sinp + s * 128 + gd * 8;
        f16x8 o1, o2;
#pragma unroll
        for (int j = 0; j < 8; j++) {
            float a = (float)x1[j], b = (float)x2[j];
            o1[j] = (f16)((a * c1[j] - b * s1[j]) * QK_SCALE_LOG2);
            o2[j] = (f16)((b * c1[j + 64] + a * s1[j + 64]) * QK_SCALE_LOG2);
        }
        *(f16x8*)(q16 + b1) = o1;
        *(f16x8*)(q16 + b1 + 64) = o2;
    } else {
        int ii = i - 262144;
        int gd = ii & 7, kvh = (ii >> 3) & 7, s = ii >> 6;
        size_t b1 = (size_t)s * 1024 + kvh * 128 + gd * 8;
        f16x8 x1 = *(const f16x8*)(kraw + b1);
        f16x8 x2 = *(const f16x8*)(kraw + b1 + 64);
        const float* c1 = cosp + s * 128 + gd * 8;
        const float* s1 = sinp + s * 128 + gd * 8;
        f16x8 o1, o2;
#pragma unroll
        for (int j = 0; j < 8; j++) {
            float a = (float)x1[j], b = (float)x2[j];
            o1[j] = (f16)(a * c1[j] - b * s1[j]);
            o2[j] = (f16)(b * c1[j + 64] + a * s1[j + 64]);
        }
        size_t dst = ((size_t)kvh * LCTX + PASTN + s) * 128 + gd * 8;
        *(f16x8*)(ck + dst) = o1;
        *(f16x8*)(ck + dst + 64) = o2;
    }
}

// ---------------------------------------------------------------------------
// Flash attention PARTIAL: 2-way KV-split, KVBLK=64 (round-13 clean core).
// Grid 512: z=b>>8, idx=b&255, h=idx&31, jj=idx>>5, j = z?7-jj:jj, s0=j*128.
// ---------------------------------------------------------------------------
__global__ __launch_bounds__(256, 2) void attn_part(
    const f16* __restrict__ Q, const f16* __restrict__ Kc,
    const f16* __restrict__ Vc, f16* __restrict__ Op, float* __restrict__ mlb)
{
    const int b = blockIdx.x;
    const int z = b >> 8;
    const int idx = b & 255;
    const int h = idx & 31;
    const int jj = idx >> 5;
    const int j = z ? (7 - jj) : jj;
    const int s0 = j * 128;
    const int kvh = h >> 2;
    const int t = threadIdx.x, lane = t & 63, w = t >> 6;
    const int l16 = lane & 15, g16 = lane >> 4;

    __shared__ f16 Ks[2][64 * 128];
    __shared__ f16 Vs[2][64 * 128];

    f16x8 qfA[4], qfB[4];
    {
        size_t baseA = (size_t)(s0 + w * 32 + l16) * 4096 + h * 128;
        size_t baseB = baseA + (size_t)16 * 4096;
#pragma unroll
        for (int kk = 0; kk < 4; kk++) {
            qfA[kk] = *(const f16x8*)(Q + baseA + kk * 32 + g16 * 8);
            qfB[kk] = *(const f16x8*)(Q + baseB + kk * 32 + g16 * 8);
        }
    }

    f32x4 ofA[8], ofB[8];
#pragma unroll
    for (int cf = 0; cf < 8; cf++) {
        ofA[cf] = (f32x4){0.f, 0.f, 0.f, 0.f};
        ofB[cf] = (f32x4){0.f, 0.f, 0.f, 0.f};
    }
    float mrA = -3.0e38f, lrA = 0.f;
    float mrB = -3.0e38f, lrB = 0.f;

    const f16* Kb = Kc + (size_t)kvh * LCTX * 128;
    const f16* Vb = Vc + (size_t)kvh * LCTX * 128;
    const int ntt = (PASTN + s0 + 128) >> 6;    // even

    const int krow = lane >> 4;
    const int kp   = lane & 15;
    const int vrow = ((lane >> 5) << 4) + (((lane >> 3) & 3) << 2) + ((lane >> 1) & 3);
    const int vch  = (lane & 1) << 3;

    const uint32_t vs0 = lds_lo(Vs[0]) + lane * 8;
    const uint32_t vs1 = lds_lo(Vs[1]) + lane * 8;

#define STAGE_KV(l0, buf)                                                     \
    {                                                                         \
        _Pragma("unroll")                                                     \
        for (int jx = 0; jx < 4; jx++) {                                      \
            int r7 = ((jx & 1) << 2) + krow;                                  \
            int sg = kp ^ r7;                                                 \
            gl_lds16(Kb + (size_t)((l0) + w * 16 + jx * 4 + krow) * 128 + sg * 8, \
                     (void*)(Ks[buf] + (w * 16 + jx * 4) * 128));             \
        }                                                                     \
        _Pragma("unroll")                                                     \
        for (int q = 0; q < 4; q++) {                                         \
            gl_lds16(Vb + (size_t)((l0) + (q & 1) * 32 + vrow) * 128          \
                        + (w * 2 + (q >> 1)) * 16 + vch,                      \
                     (void*)(Vs[buf] + (w * 4 + q) * 512));                   \
        }                                                                     \
    }

    STAGE_KV(z * 64, 0);
    __syncthreads();

    int itp = 0;
    for (int it = z; it < ntt; it += 2, ++itp) {
        const int l0 = it << 6;
        const int cur = itp & 1;

        if (it + 2 < ntt) STAGE_KV(l0 + 128, cur ^ 1);

        f32x4 sA[4], sB[4];
#pragma unroll
        for (int ni = 0; ni < 4; ni++) {
            sA[ni] = (f32x4){0.f, 0.f, 0.f, 0.f};
            sB[ni] = (f32x4){0.f, 0.f, 0.f, 0.f};
        }
        __builtin_amdgcn_s_setprio(1);
#pragma unroll
        for (int ni = 0; ni < 4; ni++)
#pragma unroll
            for (int kk = 0; kk < 4; kk++) {
                int r = ni * 16 + l16;
                int g = kk * 4 + g16;
                f16x8 kh = *(const f16x8*)&Ks[cur][r * 128 + ((g ^ (r & 7)) << 3)];
                sA[ni] = mfma16(kh, qfA[kk], sA[ni]);
                sB[ni] = mfma16(kh, qfB[kk], sB[ni]);
            }
        __builtin_amdgcn_s_setprio(0);

#define SOFTMAX(sf, mr, lr, of, QOFF)                                          \
        {                                                                      \
            const int qrow = s0 + w * 32 + (QOFF) + l16;                       \
            if (l0 + 63 > PASTN + s0 + w * 32 + (QOFF)) {                      \
                _Pragma("unroll")                                              \
                for (int ni = 0; ni < 4; ni++)                                 \
                    _Pragma("unroll")                                          \
                    for (int r = 0; r < 4; r++) {                              \
                        int col = l0 + ni * 16 + (g16 << 2) + r;               \
                        if (col > PASTN + qrow) sf[ni][r] = -3.0e38f;          \
                    }                                                          \
            }                                                                  \
            float mx;                                                          \
            {                                                                  \
                f32x4 m4 = sf[0];                                              \
                _Pragma("unroll")                                              \
                for (int ni = 1; ni < 4; ni++) {                               \
                    m4[0] = fmaxf(m4[0], sf[ni][0]);                           \
                    m4[1] = fmaxf(m4[1], sf[ni][1]);                           \
                    m4[2] = fmaxf(m4[2], sf[ni][2]);                           \
                    m4[3] = fmaxf(m4[3], sf[ni][3]);                           \
                }                                                              \
                mx = fmaxf(fmaxf(m4[0], m4[1]), fmaxf(m4[2], m4[3]));          \
            }                                                                  \
            mx = fmaxf(mx, __shfl_xor(mx, 16));                                \
            mx = fmaxf(mx, __shfl_xor(mx, 32));                                \
            if (__any(mx > mr + RESC_THR)) {                                   \
                float mnew = fmaxf(mr, mx);                                    \
                float corr = exp2f(mr - mnew);                                 \
                mr = mnew;                                                     \
                lr *= corr;                                                    \
                float cr[4];                                                   \
                _Pragma("unroll")                                              \
                for (int r = 0; r < 4; r++) cr[r] = __shfl(corr, (g16 << 2) + r); \
                _Pragma("unroll")                                              \
                for (int cf = 0; cf < 8; cf++)                                 \
                    _Pragma("unroll")                                          \
                    for (int r = 0; r < 4; r++) of[cf][r] *= cr[r];            \
            }                                                                  \
            _Pragma("unroll")                                                  \
            for (int ni = 0; ni < 4; ni++)                                     \
                _Pragma("unroll")                                              \
                for (int r = 0; r < 4; r++) {                                  \
                    float p = exp2f(sf[ni][r] - mr);                           \
                    sf[ni][r] = p;                                             \
                    lr += p;                                                   \
                }                                                              \
        }

        SOFTMAX(sA, mrA, lrA, ofA, 0)
        SOFTMAX(sB, mrB, lrB, ofB, 16)

        f16x4 paA[4], paB[4];
#pragma unroll
        for (int ni = 0; ni < 4; ni++) {
            paA[ni][0] = (f16)sA[ni][0]; paA[ni][1] = (f16)sA[ni][1];
            paA[ni][2] = (f16)sA[ni][2]; paA[ni][3] = (f16)sA[ni][3];
            paB[ni][0] = (f16)sB[ni][0]; paB[ni][1] = (f16)sB[ni][1];
            paB[ni][2] = (f16)sB[ni][2]; paB[ni][3] = (f16)sB[ni][3];
        }

        {
            const uint32_t va = cur ? vs1 : vs0;
            f16x4 ra0, ra1, ra2, ra3, rb0, rb1, rb2, rb3;
            f16x4 rc0, rc1, rc2, rc3, rd0, rd1, rd2, rd3;
            __builtin_amdgcn_s_setprio(1);
            TRRD(ra0,va,0);     TRRD(ra1,va,512);   TRRD(ra2,va,1024);  TRRD(ra3,va,1536);
            TRRD(rb0,va,2048);  TRRD(rb1,va,2560);  TRRD(rb2,va,3072);  TRRD(rb3,va,3584);
            TRRD(rc0,va,4096);  TRRD(rc1,va,4608);  TRRD(rc2,va,5120);  TRRD(rc3,va,5632);
#define X2(cf, ni, reg) \
            ofA[cf] = mfma16k16(paA[ni], reg, ofA[cf]); \
            ofB[cf] = mfma16k16(paB[ni], reg, ofB[cf]);
            WAITL(8);
            X2(0,0,ra0) X2(0,1,ra1) X2(0,2,ra2) X2(0,3,ra3)
            TRRD(rd0,va,6144);  TRRD(rd1,va,6656);  TRRD(rd2,va,7168);  TRRD(rd3,va,7680);
            WAITL(8);
            X2(1,0,rb0) X2(1,1,rb1) X2(1,2,rb2) X2(1,3,rb3)
            TRRD(ra0,va,8192);  TRRD(ra1,va,8704);  TRRD(ra2,va,9216);  TRRD(ra3,va,9728);
            WAITL(8);
            X2(2,0,rc0) X2(2,1,rc1) X2(2,2,rc2) X2(2,3,rc3)
            TRRD(rb0,va,10240); TRRD(rb1,va,10752); TRRD(rb2,va,11264); TRRD(rb3,va,11776);
            WAITL(8);
            X2(3,0,rd0) X2(3,1,rd1) X2(3,2,rd2) X2(3,3,rd3)
            TRRD(rc0,va,12288); TRRD(rc1,va,12800); TRRD(rc2,va,13312); TRRD(rc3,va,13824);
            WAITL(8);
            X2(4,0,ra0) X2(4,1,ra1) X2(4,2,ra2) X2(4,3,ra3)
            TRRD(rd0,va,14336); TRRD(rd1,va,14848); TRRD(rd2,va,15360); TRRD(rd3,va,15872);
            WAITL(8);
            X2(5,0,rb0) X2(5,1,rb1) X2(5,2,rb2) X2(5,3,rb3)
            WAITL(4);
            X2(6,0,rc0) X2(6,1,rc1) X2(6,2,rc2) X2(6,3,rc3)
            WAITL(0);
            X2(7,0,rd0) X2(7,1,rd1) X2(7,2,rd2) X2(7,3,rd3)
#undef X2
            __builtin_amdgcn_s_setprio(0);
        }
        __syncthreads();
    }

#define WRITE_P(of, mr, lr, QOFF)                                             \
    {                                                                         \
        float l2 = lr + __shfl_xor(lr, 16);                                   \
        l2 += __shfl_xor(l2, 32);                                             \
        if (lane < 16) {                                                      \
            int srow = s0 + w * 32 + (QOFF) + lane;                           \
            *(float2*)(mlb + (((size_t)z * 1024 + srow) * 32 + h) * 2) =      \
                make_float2(mr, l2);                                          \
        }                                                                     \
        float lrr[4];                                                         \
        _Pragma("unroll")                                                     \
        for (int r = 0; r < 4; r++) lrr[r] = __shfl(l2, (g16 << 2) + r);      \
        _Pragma("unroll")                                                     \
        for (int cf = 0; cf < 8; cf++)                                        \
            _Pragma("unroll")                                                 \
            for (int r = 0; r < 4; r++) {                                     \
                int srow = s0 + w * 32 + (QOFF) + (g16 << 2) + r;             \
                int d = cf * 16 + l16;                                        \
                Op[(size_t)z * 4194304 + (size_t)srow * 4096                  \
                   + (size_t)h * 128 + d] = (f16)(of[cf][r] / lrr[r]);        \
            }                                                                 \
    }
    WRITE_P(ofA, mrA, lrA, 0)
    WRITE_P(ofB, mrB, lrB, 16)
#undef WRITE_P
#undef SOFTMAX
#undef STAGE_KV
}

// ---------------------------------------------------------------------------
// combine: obuf = (O0*l0*w0 + O1*l1*w1) / (l0*w0 + l1*w1), wi = 2^(mi - m*)
// ---------------------------------------------------------------------------
__global__ void attn_combine(const f16* __restrict__ Op, const float* __restrict__ mlb,
                             f16* __restrict__ obuf)
{
    int i = blockIdx.x * 256 + threadIdx.x;
    int d8 = i & 15, hh = (i >> 4) & 31, s = i >> 9;
    float2 ml0 = *(const float2*)(mlb + (((size_t)0 * 1024 + s) * 32 + hh) * 2);
    float2 ml1 = *(const float2*)(mlb + (((size_t)1 * 1024 + s) * 32 + hh) * 2);
    float mstar = fmaxf(ml0.x, ml1.x);
    float w0 = exp2f(ml0.x - mstar) * ml0.y;
    float w1 = exp2f(ml1.x - mstar) * ml1.y;
    float inv = 1.0f / (w0 + w1);
    size_t off = (size_t)s * 4096 + (size_t)hh * 128 + d8 * 8;
    f16x8 a = *(const f16x8*)(Op + off);
    f16x8 b = *(const f16x8*)(Op + 4194304 + off);
    f16x8 o;
#pragma unroll
    for (int jx = 0; jx < 8; jx++)
        o[jx] = (f16)(((float)a[jx] * w0 + (float)b[jx] * w1) * inv);
    *(f16x8*)(obuf + off) = o;
}

// ---------------------------------------------------------------------------
// launcher
// ---------------------------------------------------------------------------
extern "C" void kernel_launch(void* const* d_in, const int* in_sizes, int n_in,
                              void* d_out, int out_size, void* d_ws, size_t ws_size,
                              hipStream_t stream)
{
    const float* hidden = (const float*)d_in[0];
    const float* kvp    = (const float*)d_in[1];
    const float* cosp   = (const float*)d_in[7];
    const float* sinp   = (const float*)d_in[8];
    const float* Wq     = (const float*)d_in[9];
    const float* Wk     = (const float*)d_in[10];
    const float* Wv     = (const float*)d_in[11];
    const float* Wo     = (const float*)d_in[12];
    const int*   layer  = (const int*)d_in[13];

    char* ws = (char*)d_ws;
    f16* w16  = (f16*)ws;                   // [0,32): Wo f16 (gemm<0> aux blocks)
    f16* opart= (f16*)(ws + 33554432);      // 16 MB: attn O partials
    f16* h16  = (f16*)(ws + 50331648);      //  8 MB: hidden fp16
    f16* ck   = (f16*)(ws + 58720256);      //  6 MB: K cache fp16
    f16* cv   = (f16*)(ws + 65011712);      //  6 MB: V cache fp16
    f16* obuf = (f16*)(ws + 71303168);      //  8 MB: combined attn out

    f16*   q16  = (f16*)d_out;                      // 8 MB scratch in d_out
    f16*   kraw = (f16*)((char*)d_out + 8388608);   // 2 MB; dead after aux2
    float* mlb  = (float*)((char*)d_out + 8388608); // 512 KB (over kraw)

    // 1) hidden fp32 -> fp16
    cvt_h<<<4096, 256, 0, stream>>>(hidden, h16);

    // 2) fused QKV projection (fp32 weights, depth-1 pipelined B-cvt)
    //    + aux blocks: cached-KV convert + Wo fp32->f16 (512 blocks, 2/CU)
    gemm_f16<0, 128><<<dim3(512), 256, 0, stream>>>(
        h16, nullptr, Wq, Wk, Wv, nullptr, q16, kraw, cv, 1024, 6144, 4096,
        kvp, layer, ck, Wo, w16);

    // 3) RoPE q/k
    aux2<<<1280, 256, 0, stream>>>(q16, kraw, cosp, sinp, ck);

    // 4) flash attention partial (clean critical path, no epilogue work)
    attn_part<<<dim3(512), 256, 0, stream>>>(q16, ck, cv, opart, mlb);

    // 5) combine partials -> obuf
    attn_combine<<<2048, 256, 0, stream>>>(opart, mlb, obuf);

    // 6) output projection, split-M 64x128 tiles (512 blocks = 2/CU) -> fp32
    gemm_f16<1, 64><<<dim3(512), 256, 0, stream>>>(
        obuf, w16, nullptr, nullptr, nullptr, (float*)d_out, nullptr, nullptr,
        nullptr, 1024, 4096, 4096, nullptr, nullptr, nullptr, nullptr, nullptr);
}

// Round 23
// 238.889 us; speedup vs baseline: 1.1569x; 1.0237x over previous
//
#include <hip/hip_runtime.h>
#include <cstdint>
#include <cstddef>

// ---------------------------------------------------------------------------
// L4maAttention, fp16 pipeline (round 23 = round 22 + QKV tile 256x64):
//   cvt_h ->
//   gemm_qkv (BM=256, BN=64: fp32 B re-reads halved, per-thread B-chain
//             halved; depth-1 dbuf; 384 GEMM + 128 aux blocks) ->
//   aux2 (RoPE q/k) -> attn_part (2-way KV-split) -> combine ->
//   gemm<1> O-proj (split-M 64, f16 Wo) -> d_out fp32.
// ---------------------------------------------------------------------------

typedef _Float16 f16;
typedef f16 f16x8 __attribute__((ext_vector_type(8)));
typedef f16 f16x4 __attribute__((ext_vector_type(4)));
typedef float f32x4 __attribute__((ext_vector_type(4)));

#define HIDN 4096
#define LCTX 3072
#define PASTN 2048
#define QK_SCALE_LOG2 0.12753102734366334f
#define RESC_THR 11.54f

__device__ __forceinline__ f32x4 mfma16(f16x8 a, f16x8 b, f32x4 c) {
    return __builtin_amdgcn_mfma_f32_16x16x32_f16(a, b, c, 0, 0, 0);
}
__device__ __forceinline__ f32x4 mfma16k16(f16x4 a, f16x4 b, f32x4 c) {
    return __builtin_amdgcn_mfma_f32_16x16x16f16(a, b, c, 0, 0, 0);
}

__device__ __forceinline__ void gl_lds16(const void* g, void* l) {
    auto gp = (const __attribute__((address_space(1))) unsigned int*)(uintptr_t)g;
    auto lp = (__attribute__((address_space(3))) unsigned int*)(uintptr_t)l;
    __builtin_amdgcn_global_load_lds(gp, lp, 16, 0, 0);
}

__device__ __forceinline__ uint32_t lds_lo(const void* p) {
    return (uint32_t)(uintptr_t)p;
}

#define TRRD(dst, va, OFF) \
    asm volatile("ds_read_b64_tr_b16 %0, %1 offset:" #OFF : "=v"(dst) : "v"(va))
#define WAITL(N) \
    asm volatile("s_waitcnt lgkmcnt(" #N ")" ::: "memory"); \
    __builtin_amdgcn_sched_barrier(0)

// ---------------------------------------------------------------------------
// cvt_h: hidden fp32 -> fp16 only (1,048,576 f4 = 4096 x 256)
// ---------------------------------------------------------------------------
__global__ void cvt_h(const float* __restrict__ hidden, f16* __restrict__ h16)
{
    int i = blockIdx.x * 256 + threadIdx.x;
    f32x4 v = *(const f32x4*)(hidden + (size_t)i * 4);
    f16x4 h;
#pragma unroll
    for (int j = 0; j < 4; j++) h[j] = (f16)v[j];
    *(f16x4*)(h16 + (size_t)i * 4) = h;
}

// ---------------------------------------------------------------------------
// gemm_qkv: C[1024,6144] = h16 @ W^T. Tile 256x64 (BM=256, BN=64, BK=64).
// 256 threads, 4 waves (2x2; wave tile 128x32, acc[8][2]).
// A = h16 via gl_lds (dbuf, 64 KB); B = fp32 Wq/Wk/Wv reg-staged + cvt
// (dbuf 16 KB) -> 80 KB LDS, 2 blocks/CU. B re-read factor 4 (vs 8 at BM=128).
// Grid 512: blocks 0..383 GEMM (4 Mx96 N tiles); 384..511 aux (cached-KV
// conv + Wo fp32->f16 slice).
// ---------------------------------------------------------------------------
__global__ __launch_bounds__(256, 2) void gemm_qkv(
    const f16* __restrict__ A,
    const float* __restrict__ Bq, const float* __restrict__ Bk2,
    const float* __restrict__ Bv2,
    f16* __restrict__ Cq, f16* __restrict__ Ck, f16* __restrict__ Cv,
    const float* __restrict__ kvp, const int* __restrict__ layer,
    f16* __restrict__ ckc, const float* __restrict__ Wo, f16* __restrict__ w16o)
{
    constexpr int K = 4096;
    __shared__ f16 As[2 * 256 * 64];   // 64 KB
    __shared__ f16 Bs[2 * 64 * 64];    // 16 KB

    const int bx = blockIdx.x;

    if (bx >= 384) {
        const int lay = layer[0];
        const int cid = bx - 384;                      // 0..127
        int base = cid * 256 + threadIdx.x;            // 0..32767
        // ---- cached-KV fp32 -> f16 (1,048,576 f4 over 128 blocks) ----
#pragma unroll
        for (int pass = 0; pass < 32; ++pass) {
            int i4 = base + pass * 32768;              // 0..1048575
            int half = i4 >> 19;
            int e = (i4 & 524287) * 4;
            int hh = e >> 18, rem = e & 262143, l = rem >> 7, d = rem & 127;
            int blk = l >> 4, rr = l & 15;
            size_t src = (((size_t)(lay * 2 + half) * 256 + blk) * 8 + hh) * 2048
                       + (size_t)rr * 128 + d;
            f32x4 x = *(const f32x4*)(kvp + src);
            f16x4 h;
#pragma unroll
            for (int j = 0; j < 4; j++) h[j] = (f16)x[j];
            size_t dst = ((size_t)hh * LCTX + l) * 128 + d;
            *(f16x4*)((half ? Cv : ckc) + dst) = h;
        }
        // ---- Wo fp32 -> f16 slice (4,194,304 f4 over 128 blocks) ----
        {
            const float* src = Wo + (size_t)cid * 131072;   // 32768 f4
            f16* dst = w16o + (size_t)cid * 131072;
#pragma unroll 4
            for (int p = 0; p < 128; ++p) {
                int e = (p * 256 + threadIdx.x) * 4;
                f32x4 v = *(const f32x4*)(src + e);
                f16x4 hv;
#pragma unroll
                for (int jx = 0; jx < 4; jx++) hv[jx] = (f16)v[jx];
                *(f16x4*)(dst + e) = hv;
            }
        }
        return;
    }

    const int t = threadIdx.x, lane = t & 63, w = t >> 6;
    const int wm = w >> 1, wn = w & 1;          // 2x2 wave grid
    const int l16 = lane & 15, g16 = lane >> 4;
    const int m0 = (bx / 96) * 256, n0 = (bx % 96) * 64;

    const int srow = lane >> 3;
    const int sgr  = (lane & 7) ^ srow;
    const size_t aoff = (size_t)(m0 + w * 64 + srow) * K + sgr * 8;

    const float* Bf;
    int nb = n0;
    if (n0 >= 5120)      { Bf = Bv2; nb = n0 - 5120; }
    else if (n0 >= 4096) { Bf = Bk2; nb = n0 - 4096; }
    else                 { Bf = Bq; }
    const int brw = lane >> 4;                // 0..3 row within 4-row group
    const int b4  = lane & 15;                // f32x4 column slot
    const int bg  = b4 >> 1, bsub = (b4 & 1) << 2;
    const float* bbase = Bf + (size_t)(nb + w * 16 + brw) * K + b4 * 4;

    int bwr[4];
#pragma unroll
    for (int j = 0; j < 4; j++) {
        int r = w * 16 + j * 4 + brw;
        bwr[j] = r * 64 + ((bg ^ (r & 7)) << 3) + bsub;
    }

    f32x4 acc[8][2];
#pragma unroll
    for (int i = 0; i < 8; i++)
#pragma unroll
        for (int j = 0; j < 2; j++) acc[i][j] = (f32x4){0.f, 0.f, 0.f, 0.f};

    f32x4 bv[4];
    // prologue: tile 0
#pragma unroll
    for (int j = 0; j < 4; j++)
        bv[j] = *(const f32x4*)(bbase + (size_t)(j * 4) * K);
#pragma unroll
    for (int j = 0; j < 8; j++)
        gl_lds16(A + aoff + (size_t)j * 8 * K,
                 (void*)(As + (w * 64 + j * 8) * 64));
#pragma unroll
    for (int j = 0; j < 4; j++) {
        f16x4 hv;
#pragma unroll
        for (int q = 0; q < 4; q++) hv[q] = (f16)bv[j][q];
        *(f16x4*)&Bs[bwr[j]] = hv;
    }
    __syncthreads();

    for (int k0 = 0; k0 < K; k0 += 64) {
        const int cur = (k0 >> 6) & 1;
        const int nxt = cur ^ 1;
        const bool more = (k0 + 64 < K);
        if (more) {
#pragma unroll
            for (int j = 0; j < 8; j++)
                gl_lds16(A + aoff + (size_t)j * 8 * K + k0 + 64,
                         (void*)(As + nxt * 16384 + (w * 64 + j * 8) * 64));
#pragma unroll
            for (int j = 0; j < 4; j++)
                bv[j] = *(const f32x4*)(bbase + (size_t)(j * 4) * K + k0 + 64);
        }
#pragma unroll
        for (int ks = 0; ks < 2; ks++) {
            f16x8 af[8], bfr[2];
#pragma unroll
            for (int mi = 0; mi < 8; mi++) {
                int r = wm * 128 + mi * 16 + l16;
                int g = ks * 4 + g16;
                af[mi] = *(const f16x8*)&As[cur * 16384 + r * 64 + ((g ^ (r & 7)) << 3)];
            }
#pragma unroll
            for (int ni = 0; ni < 2; ni++) {
                int r = wn * 32 + ni * 16 + l16;
                int g = ks * 4 + g16;
                bfr[ni] = *(const f16x8*)&Bs[cur * 4096 + r * 64 + ((g ^ (r & 7)) << 3)];
            }
#pragma unroll
            for (int ni = 0; ni < 2; ni++)
#pragma unroll
                for (int mi = 0; mi < 8; mi++)
                    acc[mi][ni] = mfma16(af[mi], bfr[ni], acc[mi][ni]);
        }
        if (more) {
#pragma unroll
            for (int j = 0; j < 4; j++) {
                f16x4 hv;
#pragma unroll
                for (int q = 0; q < 4; q++) hv[q] = (f16)bv[j][q];
                *(f16x4*)&Bs[nxt * 4096 + bwr[j]] = hv;
            }
        }
        __syncthreads();
    }

#pragma unroll
    for (int mi = 0; mi < 8; mi++)
#pragma unroll
        for (int ni = 0; ni < 2; ni++)
#pragma unroll
            for (int r = 0; r < 4; r++) {
                int row = m0 + wm * 128 + mi * 16 + (g16 << 2) + r;
                int col = n0 + wn * 32 + ni * 16 + l16;
                float val = acc[mi][ni][r];
                if (col < 4096) {
                    Cq[(size_t)row * 4096 + col] = (f16)val;
                } else if (col < 5120) {
                    Ck[(size_t)row * 1024 + (col - 4096)] = (f16)val;
                } else {
                    int c = col - 5120;
                    int hh = c >> 7, d = c & 127;
                    Cv[((size_t)hh * LCTX + PASTN + row) * 128 + d] = (f16)val;
                }
            }
}

// ---------------------------------------------------------------------------
// gemm_o: d_out[1024,4096] fp32 = obuf @ Wo16^T. BM=64 split-M, 256 threads,
// grid 512 (32x16 tiles), single-buffer gl_lds (round-19 proven).
// ---------------------------------------------------------------------------
__global__ __launch_bounds__(256, 3) void gemm_o(
    const f16* __restrict__ A, const f16* __restrict__ Bh,
    float* __restrict__ Cf)
{
    constexpr int K = 4096;
    __shared__ f16 As[64 * 64];
    __shared__ f16 Bs[128 * 64];

    const int bx = blockIdx.x;
    const int t = threadIdx.x, lane = t & 63, w = t >> 6;
    const int wm = w >> 1, wn = w & 1;
    const int l16 = lane & 15, g16 = lane >> 4;
    const int m0 = (bx / 32) * 64, n0 = (bx % 32) * 128;

    const int srow = lane >> 3;
    const int sgr  = (lane & 7) ^ srow;

    const size_t aoff = (size_t)(m0 + w * 16 + srow) * K + sgr * 8;
    const size_t boff = (size_t)(n0 + w * 32 + srow) * K + sgr * 8;

    f32x4 acc[2][4];
#pragma unroll
    for (int i = 0; i < 2; i++)
#pragma unroll
        for (int j = 0; j < 4; j++) acc[i][j] = (f32x4){0.f, 0.f, 0.f, 0.f};

    for (int k0 = 0; k0 < K; k0 += 64) {
#pragma unroll
        for (int j = 0; j < 2; j++)
            gl_lds16(A + aoff + (size_t)j * 8 * K + k0,
                     (void*)(As + (w * 16 + j * 8) * 64));
#pragma unroll
        for (int j = 0; j < 4; j++)
            gl_lds16(Bh + boff + (size_t)j * 8 * K + k0,
                     (void*)(Bs + (w * 32 + j * 8) * 64));
        __syncthreads();

#pragma unroll
        for (int ks = 0; ks < 2; ks++) {
            f16x8 af[2], bfr[4];
#pragma unroll
            for (int mi = 0; mi < 2; mi++) {
                int r = wm * 32 + mi * 16 + l16;
                int g = ks * 4 + g16;
                af[mi] = *(const f16x8*)&As[r * 64 + ((g ^ (r & 7)) << 3)];
            }
#pragma unroll
            for (int ni = 0; ni < 4; ni++) {
                int r = wn * 64 + ni * 16 + l16;
                int g = ks * 4 + g16;
                bfr[ni] = *(const f16x8*)&Bs[r * 64 + ((g ^ (r & 7)) << 3)];
            }
#pragma unroll
            for (int ni = 0; ni < 4; ni++)
#pragma unroll
                for (int mi = 0; mi < 2; mi++)
                    acc[mi][ni] = mfma16(af[mi], bfr[ni], acc[mi][ni]);
        }
        __syncthreads();
    }

#pragma unroll
    for (int mi = 0; mi < 2; mi++)
#pragma unroll
        for (int ni = 0; ni < 4; ni++)
#pragma unroll
            for (int r = 0; r < 4; r++) {
                int row = m0 + wm * 32 + mi * 16 + (g16 << 2) + r;
                int col = n0 + wn * 64 + ni * 16 + l16;
                Cf[(size_t)row * 4096 + col] = acc[mi][ni][r];
            }
}

// ---------------------------------------------------------------------------
// aux2: RoPE only. rope_q (262,144) + rope_k (65,536) = 327,680 = 1280 x 256.
// ---------------------------------------------------------------------------
__global__ void aux2(f16* __restrict__ q16, const f16* __restrict__ kraw,
                     const float* __restrict__ cosp, const float* __restrict__ sinp,
                     f16* __restrict__ ck)
{
    int i = blockIdx.x * 256 + threadIdx.x;
    if (i < 262144) {
        int gd = i & 7, hh = (i >> 3) & 31, s = i >> 8;
        size_t b1 = (size_t)s * 4096 + hh * 128 + gd * 8;
        f16x8 x1 = *(f16x8*)(q16 + b1);
        f16x8 x2 = *(f16x8*)(q16 + b1 + 64);
        const float* c1 = cosp + s * 128 + gd * 8;
        const float* s1 = sinp + s * 128 + gd * 8;
        f16x8 o1, o2;
#pragma unroll
        for (int j = 0; j < 8; j++) {
            float a = (float)x1[j], b = (float)x2[j];
            o1[j] = (f16)((a * c1[j] - b * s1[j]) * QK_SCALE_LOG2);
            o2[j] = (f16)((b * c1[j + 64] + a * s1[j + 64]) * QK_SCALE_LOG2);
        }
        *(f16x8*)(q16 + b1) = o1;
        *(f16x8*)(q16 + b1 + 64) = o2;
    } else {
        int ii = i - 262144;
        int gd = ii & 7, kvh = (ii >> 3) & 7, s = ii >> 6;
        size_t b1 = (size_t)s * 1024 + kvh * 128 + gd * 8;
        f16x8 x1 = *(const f16x8*)(kraw + b1);
        f16x8 x2 = *(const f16x8*)(kraw + b1 + 64);
        const float* c1 = cosp + s * 128 + gd * 8;
        const float* s1 = sinp + s * 128 + gd * 8;
        f16x8 o1, o2;
#pragma unroll
        for (int j = 0; j < 8; j++) {
            float a = (float)x1[j], b = (float)x2[j];
            o1[j] = (f16)(a * c1[j] - b * s1[j]);
            o2[j] = (f16)(b * c1[j + 64] + a * s1[j + 64]);
        }
        size_t dst = ((size_t)kvh * LCTX + PASTN + s) * 128 + gd * 8;
        *(f16x8*)(ck + dst) = o1;
        *(f16x8*)(ck + dst + 64) = o2;
    }
}

// ---------------------------------------------------------------------------
// Flash attention PARTIAL: 2-way KV-split, KVBLK=64 (round-13 clean core).
// Grid 512: z=b>>8, idx=b&255, h=idx&31, jj=idx>>5, j = z?7-jj:jj, s0=j*128.
// ---------------------------------------------------------------------------
__global__ __launch_bounds__(256, 2) void attn_part(
    const f16* __restrict__ Q, const f16* __restrict__ Kc,
    const f16* __restrict__ Vc, f16* __restrict__ Op, float* __restrict__ mlb)
{
    const int b = blockIdx.x;
    const int z = b >> 8;
    const int idx = b & 255;
    const int h = idx & 31;
    const int jj = idx >> 5;
    const int j = z ? (7 - jj) : jj;
    const int s0 = j * 128;
    const int kvh = h >> 2;
    const int t = threadIdx.x, lane = t & 63, w = t >> 6;
    const int l16 = lane & 15, g16 = lane >> 4;

    __shared__ f16 Ks[2][64 * 128];
    __shared__ f16 Vs[2][64 * 128];

    f16x8 qfA[4], qfB[4];
    {
        size_t baseA = (size_t)(s0 + w * 32 + l16) * 4096 + h * 128;
        size_t baseB = baseA + (size_t)16 * 4096;
#pragma unroll
        for (int kk = 0; kk < 4; kk++) {
            qfA[kk] = *(const f16x8*)(Q + baseA + kk * 32 + g16 * 8);
            qfB[kk] = *(const f16x8*)(Q + baseB + kk * 32 + g16 * 8);
        }
    }

    f32x4 ofA[8], ofB[8];
#pragma unroll
    for (int cf = 0; cf < 8; cf++) {
        ofA[cf] = (f32x4){0.f, 0.f, 0.f, 0.f};
        ofB[cf] = (f32x4){0.f, 0.f, 0.f, 0.f};
    }
    float mrA = -3.0e38f, lrA = 0.f;
    float mrB = -3.0e38f, lrB = 0.f;

    const f16* Kb = Kc + (size_t)kvh * LCTX * 128;
    const f16* Vb = Vc + (size_t)kvh * LCTX * 128;
    const int ntt = (PASTN + s0 + 128) >> 6;    // even

    const int krow = lane >> 4;
    const int kp   = lane & 15;
    const int vrow = ((lane >> 5) << 4) + (((lane >> 3) & 3) << 2) + ((lane >> 1) & 3);
    const int vch  = (lane & 1) << 3;

    const uint32_t vs0 = lds_lo(Vs[0]) + lane * 8;
    const uint32_t vs1 = lds_lo(Vs[1]) + lane * 8;

#define STAGE_KV(l0, buf)                                                     \
    {                                                                         \
        _Pragma("unroll")                                                     \
        for (int jx = 0; jx < 4; jx++) {                                      \
            int r7 = ((jx & 1) << 2) + krow;                                  \
            int sg = kp ^ r7;                                                 \
            gl_lds16(Kb + (size_t)((l0) + w * 16 + jx * 4 + krow) * 128 + sg * 8, \
                     (void*)(Ks[buf] + (w * 16 + jx * 4) * 128));             \
        }                                                                     \
        _Pragma("unroll")                                                     \
        for (int q = 0; q < 4; q++) {                                         \
            gl_lds16(Vb + (size_t)((l0) + (q & 1) * 32 + vrow) * 128          \
                        + (w * 2 + (q >> 1)) * 16 + vch,                      \
                     (void*)(Vs[buf] + (w * 4 + q) * 512));                   \
        }                                                                     \
    }

    STAGE_KV(z * 64, 0);
    __syncthreads();

    int itp = 0;
    for (int it = z; it < ntt; it += 2, ++itp) {
        const int l0 = it << 6;
        const int cur = itp & 1;

        if (it + 2 < ntt) STAGE_KV(l0 + 128, cur ^ 1);

        f32x4 sA[4], sB[4];
#pragma unroll
        for (int ni = 0; ni < 4; ni++) {
            sA[ni] = (f32x4){0.f, 0.f, 0.f, 0.f};
            sB[ni] = (f32x4){0.f, 0.f, 0.f, 0.f};
        }
        __builtin_amdgcn_s_setprio(1);
#pragma unroll
        for (int ni = 0; ni < 4; ni++)
#pragma unroll
            for (int kk = 0; kk < 4; kk++) {
                int r = ni * 16 + l16;
                int g = kk * 4 + g16;
                f16x8 kh = *(const f16x8*)&Ks[cur][r * 128 + ((g ^ (r & 7)) << 3)];
                sA[ni] = mfma16(kh, qfA[kk], sA[ni]);
                sB[ni] = mfma16(kh, qfB[kk], sB[ni]);
            }
        __builtin_amdgcn_s_setprio(0);

#define SOFTMAX(sf, mr, lr, of, QOFF)                                          \
        {                                                                      \
            const int qrow = s0 + w * 32 + (QOFF) + l16;                       \
            if (l0 + 63 > PASTN + s0 + w * 32 + (QOFF)) {                      \
                _Pragma("unroll")                                              \
                for (int ni = 0; ni < 4; ni++)                                 \
                    _Pragma("unroll")                                          \
                    for (int r = 0; r < 4; r++) {                              \
                        int col = l0 + ni * 16 + (g16 << 2) + r;               \
                        if (col > PASTN + qrow) sf[ni][r] = -3.0e38f;          \
                    }                                                          \
            }                                                                  \
            float mx;                                                          \
            {                                                                  \
                f32x4 m4 = sf[0];                                              \
                _Pragma("unroll")                                              \
                for (int ni = 1; ni < 4; ni++) {                               \
                    m4[0] = fmaxf(m4[0], sf[ni][0]);                           \
                    m4[1] = fmaxf(m4[1], sf[ni][1]);                           \
                    m4[2] = fmaxf(m4[2], sf[ni][2]);                           \
                    m4[3] = fmaxf(m4[3], sf[ni][3]);                           \
                }                                                              \
                mx = fmaxf(fmaxf(m4[0], m4[1]), fmaxf(m4[2], m4[3]));          \
            }                                                                  \
            mx = fmaxf(mx, __shfl_xor(mx, 16));                                \
            mx = fmaxf(mx, __shfl_xor(mx, 32));                                \
            if (__any(mx > mr + RESC_THR)) {                                   \
                float mnew = fmaxf(mr, mx);                                    \
                float corr = exp2f(mr - mnew);                                 \
                mr = mnew;                                                     \
                lr *= corr;                                                    \
                float cr[4];                                                   \
                _Pragma("unroll")                                              \
                for (int r = 0; r < 4; r++) cr[r] = __shfl(corr, (g16 << 2) + r); \
                _Pragma("unroll")                                              \
                for (int cf = 0; cf < 8; cf++)                                 \
                    _Pragma("unroll")                                          \
                    for (int r = 0; r < 4; r++) of[cf][r] *= cr[r];            \
            }                                                                  \
            _Pragma("unroll")                                                  \
            for (int ni = 0; ni < 4; ni++)                                     \
                _Pragma("unroll")                                              \
                for (int r = 0; r < 4; r++) {                                  \
                    float p = exp2f(sf[ni][r] - mr);                           \
                    sf[ni][r] = p;                                             \
                    lr += p;                                                   \
                }                                                              \
        }

        SOFTMAX(sA, mrA, lrA, ofA, 0)
        SOFTMAX(sB, mrB, lrB, ofB, 16)

        f16x4 paA[4], paB[4];
#pragma unroll
        for (int ni = 0; ni < 4; ni++) {
            paA[ni][0] = (f16)sA[ni][0]; paA[ni][1] = (f16)sA[ni][1];
            paA[ni][2] = (f16)sA[ni][2]; paA[ni][3] = (f16)sA[ni][3];
            paB[ni][0] = (f16)sB[ni][0]; paB[ni][1] = (f16)sB[ni][1];
            paB[ni][2] = (f16)sB[ni][2]; paB[ni][3] = (f16)sB[ni][3];
        }

        {
            const uint32_t va = cur ? vs1 : vs0;
            f16x4 ra0, ra1, ra2, ra3, rb0, rb1, rb2, rb3;
            f16x4 rc0, rc1, rc2, rc3, rd0, rd1, rd2, rd3;
            __builtin_amdgcn_s_setprio(1);
            TRRD(ra0,va,0);     TRRD(ra1,va,512);   TRRD(ra2,va,1024);  TRRD(ra3,va,1536);
            TRRD(rb0,va,2048);  TRRD(rb1,va,2560);  TRRD(rb2,va,3072);  TRRD(rb3,va,3584);
            TRRD(rc0,va,4096);  TRRD(rc1,va,4608);  TRRD(rc2,va,5120);  TRRD(rc3,va,5632);
#define X2(cf, ni, reg) \
            ofA[cf] = mfma16k16(paA[ni], reg, ofA[cf]); \
            ofB[cf] = mfma16k16(paB[ni], reg, ofB[cf]);
            WAITL(8);
            X2(0,0,ra0) X2(0,1,ra1) X2(0,2,ra2) X2(0,3,ra3)
            TRRD(rd0,va,6144);  TRRD(rd1,va,6656);  TRRD(rd2,va,7168);  TRRD(rd3,va,7680);
            WAITL(8);
            X2(1,0,rb0) X2(1,1,rb1) X2(1,2,rb2) X2(1,3,rb3)
            TRRD(ra0,va,8192);  TRRD(ra1,va,8704);  TRRD(ra2,va,9216);  TRRD(ra3,va,9728);
            WAITL(8);
            X2(2,0,rc0) X2(2,1,rc1) X2(2,2,rc2) X2(2,3,rc3)
            TRRD(rb0,va,10240); TRRD(rb1,va,10752); TRRD(rb2,va,11264); TRRD(rb3,va,11776);
            WAITL(8);
            X2(3,0,rd0) X2(3,1,rd1) X2(3,2,rd2) X2(3,3,rd3)
            TRRD(rc0,va,12288); TRRD(rc1,va,12800); TRRD(rc2,va,13312); TRRD(rc3,va,13824);
            WAITL(8);
            X2(4,0,ra0) X2(4,1,ra1) X2(4,2,ra2) X2(4,3,ra3)
            TRRD(rd0,va,14336); TRRD(rd1,va,14848); TRRD(rd2,va,15360); TRRD(rd3,va,15872);
            WAITL(8);
            X2(5,0,rb0) X2(5,1,rb1) X2(5,2,rb2) X2(5,3,rb3)
            WAITL(4);
            X2(6,0,rc0) X2(6,1,rc1) X2(6,2,rc2) X2(6,3,rc3)
            WAITL(0);
            X2(7,0,rd0) X2(7,1,rd1) X2(7,2,rd2) X2(7,3,rd3)
#undef X2
            __builtin_amdgcn_s_setprio(0);
        }
        __syncthreads();
    }

#define WRITE_P(of, mr, lr, QOFF)                                             \
    {                                                                         \
        float l2 = lr + __shfl_xor(lr, 16);                                   \
        l2 += __shfl_xor(l2, 32);                                             \
        if (lane < 16) {                                                      \
            int srow = s0 + w * 32 + (QOFF) + lane;                           \
            *(float2*)(mlb + (((size_t)z * 1024 + srow) * 32 + h) * 2) =      \
                make_float2(mr, l2);                                          \
        }                                                                     \
        float lrr[4];                                                         \
        _Pragma("unroll")                                                     \
        for (int r = 0; r < 4; r++) lrr[r] = __shfl(l2, (g16 << 2) + r);      \
        _Pragma("unroll")                                                     \
        for (int cf = 0; cf < 8; cf++)                                        \
            _Pragma("unroll")                                                 \
            for (int r = 0; r < 4; r++) {                                     \
                int srow = s0 + w * 32 + (QOFF) + (g16 << 2) + r;             \
                int d = cf * 16 + l16;                                        \
                Op[(size_t)z * 4194304 + (size_t)srow * 4096                  \
                   + (size_t)h * 128 + d] = (f16)(of[cf][r] / lrr[r]);        \
            }                                                                 \
    }
    WRITE_P(ofA, mrA, lrA, 0)
    WRITE_P(ofB, mrB, lrB, 16)
#undef WRITE_P
#undef SOFTMAX
#undef STAGE_KV
}

// ---------------------------------------------------------------------------
// combine: obuf = (O0*l0*w0 + O1*l1*w1) / (l0*w0 + l1*w1), wi = 2^(mi - m*)
// ---------------------------------------------------------------------------
__global__ void attn_combine(const f16* __restrict__ Op, const float* __restrict__ mlb,
                             f16* __restrict__ obuf)
{
    int i = blockIdx.x * 256 + threadIdx.x;
    int d8 = i & 15, hh = (i >> 4) & 31, s = i >> 9;
    float2 ml0 = *(const float2*)(mlb + (((size_t)0 * 1024 + s) * 32 + hh) * 2);
    float2 ml1 = *(const float2*)(mlb + (((size_t)1 * 1024 + s) * 32 + hh) * 2);
    float mstar = fmaxf(ml0.x, ml1.x);
    float w0 = exp2f(ml0.x - mstar) * ml0.y;
    float w1 = exp2f(ml1.x - mstar) * ml1.y;
    float inv = 1.0f / (w0 + w1);
    size_t off = (size_t)s * 4096 + (size_t)hh * 128 + d8 * 8;
    f16x8 a = *(const f16x8*)(Op + off);
    f16x8 b = *(const f16x8*)(Op + 4194304 + off);
    f16x8 o;
#pragma unroll
    for (int jx = 0; jx < 8; jx++)
        o[jx] = (f16)(((float)a[jx] * w0 + (float)b[jx] * w1) * inv);
    *(f16x8*)(obuf + off) = o;
}

// ---------------------------------------------------------------------------
// launcher
// ---------------------------------------------------------------------------
extern "C" void kernel_launch(void* const* d_in, const int* in_sizes, int n_in,
                              void* d_out, int out_size, void* d_ws, size_t ws_size,
                              hipStream_t stream)
{
    const float* hidden = (const float*)d_in[0];
    const float* kvp    = (const float*)d_in[1];
    const float* cosp   = (const float*)d_in[7];
    const float* sinp   = (const float*)d_in[8];
    const float* Wq     = (const float*)d_in[9];
    const float* Wk     = (const float*)d_in[10];
    const float* Wv     = (const float*)d_in[11];
    const float* Wo     = (const float*)d_in[12];
    const int*   layer  = (const int*)d_in[13];

    char* ws = (char*)d_ws;
    f16* w16  = (f16*)ws;                   // [0,32): Wo f16 (gemm_qkv aux blocks)
    f16* opart= (f16*)(ws + 33554432);      // 16 MB: attn O partials
    f16* h16  = (f16*)(ws + 50331648);      //  8 MB: hidden fp16
    f16* ck   = (f16*)(ws + 58720256);      //  6 MB: K cache fp16
    f16* cv   = (f16*)(ws + 65011712);      //  6 MB: V cache fp16
    f16* obuf = (f16*)(ws + 71303168);      //  8 MB: combined attn out

    f16*   q16  = (f16*)d_out;                      // 8 MB scratch in d_out
    f16*   kraw = (f16*)((char*)d_out + 8388608);   // 2 MB; dead after aux2
    float* mlb  = (float*)((char*)d_out + 8388608); // 512 KB (over kraw)

    // 1) hidden fp32 -> fp16
    cvt_h<<<4096, 256, 0, stream>>>(hidden, h16);

    // 2) fused QKV projection (256x64 tiles, fp32 weights, depth-1 B-cvt)
    //    + aux blocks: cached-KV convert + Wo fp32->f16 (512 blocks, 2/CU)
    gemm_qkv<<<dim3(512), 256, 0, stream>>>(
        h16, Wq, Wk, Wv, q16, kraw, cv, kvp, layer, ck, Wo, w16);

    // 3) RoPE q/k
    aux2<<<1280, 256, 0, stream>>>(q16, kraw, cosp, sinp, ck);

    // 4) flash attention partial (clean critical path)
    attn_part<<<dim3(512), 256, 0, stream>>>(q16, ck, cv, opart, mlb);

    // 5) combine partials -> obuf
    attn_combine<<<2048, 256, 0, stream>>>(opart, mlb, obuf);

    // 6) output projection, split-M 64x128 tiles (512 blocks = 2/CU) -> fp32
    gemm_o<<<dim3(512), 256, 0, stream>>>(obuf, w16, (float*)d_out);
}